// Round 7
// baseline (1166.478 us; speedup 1.0000x reference)
//
#include <hip/hip_runtime.h>
#include <hip/hip_fp16.h>

// N=1024, F=22, T=1000, H=64, gates 4H=256
// Diagonal pipeline (iter i: L0 t=i, L1 t=i-1, L2 t=i-2), ONE barrier/iter.
// 1024 threads = 16 waves, ONE unit per wave:
//   waves 0-3: L2 colgroup w ; 4-7: L1 ; 8-11: L0 ; 12-15: x staging.
// R7: stager prefetches x by TWO iterations (load issued one full iter before
// its waitcnt) so global-load latency never gates the barrier; bias enters as
// the C operand of the first MFMA (no per-iter acc-init movs).
#define TT 1000
#define FF 22
#define HH 64
#define BB 4       // batch per block
#define NBLK 256   // 1024/4 -> one block per CU
#define S0 112     // LDS row stride (f16) layer0 [x(0:22)|pad|h0(32:96)|pad], 3 K-tiles
#define S1 144     // LDS row stride (f16) layers1/2 [h_in(0:64)|h_rec(64:128)|pad], 4 K-tiles

typedef _Float16 half8 __attribute__((ext_vector_type(8)));
typedef float float4v __attribute__((ext_vector_type(4)));

__device__ __forceinline__ float sigm(float v) { return 1.0f / (1.0f + __expf(-v)); }
__device__ __forceinline__ float tanh_(float v) { return 1.0f - 2.0f / (__expf(2.0f * v) + 1.0f); }

// select reg q of a float4v acc (q in 0..3) with 3 cndmasks
__device__ __forceinline__ float sel4(const float4v a, int q) {
    float lo = (q & 2) ? a[2] : a[0];
    float hi = (q & 2) ? a[3] : a[1];
    return (q & 1) ? hi : lo;
}

__device__ __forceinline__ float gate_update(const float z[4], float& c) {
    float cc = sigm(z[1]) * c + sigm(z[0]) * tanh_(z[2]);
    c = cc;
    return sigm(z[3]) * tanh_(cc);
}

extern "C" __global__ void __launch_bounds__(1024, 1)
lstm_fused(const float* __restrict__ x,
           const float* __restrict__ Wih0, const float* __restrict__ Whh0,
           const float* __restrict__ bih0, const float* __restrict__ bhh0,
           const float* __restrict__ Wih1, const float* __restrict__ Whh1,
           const float* __restrict__ bih1, const float* __restrict__ bhh1,
           const float* __restrict__ Wih2, const float* __restrict__ Whh2,
           const float* __restrict__ bih2, const float* __restrict__ bhh2,
           const float* __restrict__ w0, const float* __restrict__ b0,
           const float* __restrict__ w1, const float* __restrict__ b1,
           const float* __restrict__ w2, const float* __restrict__ b2,
           const float* __restrict__ w3, const float* __restrict__ b3,
           const float* __restrict__ g0, const float* __restrict__ be0,
           const float* __restrict__ m0, const float* __restrict__ v0,
           const float* __restrict__ g1, const float* __restrict__ be1,
           const float* __restrict__ m1, const float* __restrict__ v1,
           const float* __restrict__ g2, const float* __restrict__ be2,
           const float* __restrict__ m2, const float* __restrict__ v2,
           float* __restrict__ out)
{
    __shared__ __align__(16) _Float16 in0[2 * 4 * S0];
    __shared__ __align__(16) _Float16 in1[2 * 4 * S1];
    __shared__ __align__(16) _Float16 in2[2 * 4 * S1];
    __shared__ float fcA[BB * 64];
    __shared__ float fcB[BB * 64];
    __shared__ float fcW[54 * 65];
    __shared__ float fcP[5 * 64];

    const int tid  = threadIdx.x;
    const int wv   = tid >> 6;      // 0..15
    const int role = wv >> 2;       // 0=L2, 1=L1, 2=L0, 3=stage
    const int w4   = wv & 3;        // colgroup within role
    const int l    = tid & 63;
    const int q    = l >> 4;
    const int l15  = l & 15;
    const int u    = 16 * w4 + l15; // hidden unit for this lane's update
    const int b    = q;             // batch row for this lane's update
    const int n0   = blockIdx.x * BB;

    for (int i = tid; i < 2 * 4 * S0; i += 1024) in0[i] = (_Float16)0.0f;
    for (int i = tid; i < 2 * 4 * S1; i += 1024) in1[i] = (_Float16)0.0f;
    for (int i = tid; i < 2 * 4 * S1; i += 1024) in2[i] = (_Float16)0.0f;

    // ---- weight B-fragments: ONE unit per wave (shared reg array across roles) ----
    half8 wf[4][4];
    float4v biasC[4];                // bias splat, persistent (C operand of 1st MFMA)
    if (role == 2) {                 // layer 0: K=32(x,padded)+64(h) -> 3 K-tiles
#pragma unroll
        for (int g = 0; g < 4; ++g) {
            const int row = 64 * g + u;
#pragma unroll
            for (int kt = 0; kt < 3; ++kt) {
                half8 h{};
#pragma unroll
                for (int j = 0; j < 8; ++j) {
                    const int k = 32 * kt + 8 * q + j;
                    float val = 0.0f;
                    if (k < 32) { if (k < FF) val = Wih0[row * FF + k]; }
                    else        { val = Whh0[row * HH + (k - 32)]; }
                    h[j] = (_Float16)val;
                }
                wf[g][kt] = h;
            }
            float bv = bih0[row] + bhh0[row];
            biasC[g] = float4v{bv, bv, bv, bv};
        }
    } else if (role < 2) {           // role 0 -> layer 2, role 1 -> layer 1 (K=128)
        const float* Wih = role ? Wih1 : Wih2;
        const float* Whh = role ? Whh1 : Whh2;
        const float* bih = role ? bih1 : bih2;
        const float* bhh = role ? bhh1 : bhh2;
#pragma unroll
        for (int g = 0; g < 4; ++g) {
            const int row = 64 * g + u;
#pragma unroll
            for (int kt = 0; kt < 4; ++kt) {
                half8 h{};
#pragma unroll
                for (int j = 0; j < 8; ++j) {
                    const int k = 32 * kt + 8 * q + j;
                    h[j] = (_Float16)((k < 64) ? Wih[row * HH + k] : Whh[row * HH + (k - 64)]);
                }
                wf[g][kt] = h;
            }
            float bv = bih[row] + bhh[row];
            biasC[g] = float4v{bv, bv, bv, bv};
        }
    }

    // ---- x staging lanes: waves 12-15, first 88 threads of that group ----
    const int  st  = tid - 768;
    const bool xok = (role == 3) && (st < BB * FF);
    const int  xb  = xok ? (st / FF) : 0;
    const int  xf  = xok ? (st - xb * FF) : 0;
    const float* xp = x + ((size_t)(n0 + xb) * FF + xf) * TT;

    float xh = 0.f;                 // x value for NEXT iteration's write (prefetch depth 2)
    __syncthreads();
    if (xok) {
        in0[xb * S0 + xf] = (_Float16)xp[0]; // x_0 -> parity 0
        xh = xp[1];                          // x_1, written at iter 0
    }
    __syncthreads();

    // A-frag read base: replicated rows via addressing (row = l15 & 3)
    const int arow = (role == 2) ? ((l15 & 3) * S0 + q * 8) : ((l15 & 3) * S1 + q * 8);

    float c = 0.f;  // this wave's cell state for its (layer, unit)

    auto iter_body = [&](int i, bool d0, bool d1, bool d2, bool last) {
        const int p = i & 1;
        _Float16* i0r = in0 + p * 4 * S0;  _Float16* i0w = in0 + (p ^ 1) * 4 * S0;
        _Float16* i1r = in1 + p * 4 * S1;  _Float16* i1w = in1 + (p ^ 1) * 4 * S1;
        _Float16* i2r = in2 + p * 4 * S1;  _Float16* i2w = in2 + (p ^ 1) * 4 * S1;

        if (role == 3) {
            if (d0 && xok) {
                i0w[xb * S0 + xf] = (_Float16)xh;          // x_{i+1} (loaded last iter)
                const int tn = (i + 2 < TT) ? (i + 2) : (TT - 1); // clamp never read
                xh = xp[tn];                               // waitcnt lands next iter
            }
        } else {
            const bool act = (role == 0) ? d2 : (role == 1) ? d1 : d0;
            if (act) {
                const _Float16* rd = (role == 0) ? i2r : (role == 1) ? i1r : i0r;
                float4v acc[4];
                if (role == 2) {     // 3 K-tiles
                    half8 a0 = *(const half8*)(rd + arow);
                    half8 a1 = *(const half8*)(rd + arow + 32);
                    half8 a2 = *(const half8*)(rd + arow + 64);
#pragma unroll
                    for (int g = 0; g < 4; ++g)
                        acc[g] = __builtin_amdgcn_mfma_f32_16x16x32_f16(a0, wf[g][0], biasC[g], 0, 0, 0);
#pragma unroll
                    for (int g = 0; g < 4; ++g)
                        acc[g] = __builtin_amdgcn_mfma_f32_16x16x32_f16(a1, wf[g][1], acc[g], 0, 0, 0);
#pragma unroll
                    for (int g = 0; g < 4; ++g)
                        acc[g] = __builtin_amdgcn_mfma_f32_16x16x32_f16(a2, wf[g][2], acc[g], 0, 0, 0);
                } else {             // 4 K-tiles
                    half8 a0 = *(const half8*)(rd + arow);
                    half8 a1 = *(const half8*)(rd + arow + 32);
                    half8 a2 = *(const half8*)(rd + arow + 64);
                    half8 a3 = *(const half8*)(rd + arow + 96);
#pragma unroll
                    for (int g = 0; g < 4; ++g)
                        acc[g] = __builtin_amdgcn_mfma_f32_16x16x32_f16(a0, wf[g][0], biasC[g], 0, 0, 0);
#pragma unroll
                    for (int g = 0; g < 4; ++g)
                        acc[g] = __builtin_amdgcn_mfma_f32_16x16x32_f16(a1, wf[g][1], acc[g], 0, 0, 0);
#pragma unroll
                    for (int g = 0; g < 4; ++g)
                        acc[g] = __builtin_amdgcn_mfma_f32_16x16x32_f16(a2, wf[g][2], acc[g], 0, 0, 0);
#pragma unroll
                    for (int g = 0; g < 4; ++g)
                        acc[g] = __builtin_amdgcn_mfma_f32_16x16x32_f16(a3, wf[g][3], acc[g], 0, 0, 0);
                }
                float z[4];
#pragma unroll
                for (int g = 0; g < 4; ++g) z[g] = sel4(acc[g], q);
                float h = gate_update(z, c);
                _Float16 hf = (_Float16)h;
                if (role == 2) {        // h0: own recurrence + L1 input
                    i0w[b * S0 + 32 + u] = hf;
                    i1w[b * S1 + u]      = hf;
                } else if (role == 1) { // h1: own recurrence + L2 input
                    i1w[b * S1 + 64 + u] = hf;
                    i2w[b * S1 + u]      = hf;
                } else {                // L2
                    if (last) fcA[b * 64 + u] = h;     // final h2 -> FC (fp32)
                    else      i2w[b * S1 + 64 + u] = hf;
                }
            }
        }
        __syncthreads();
    };

    iter_body(0, true, false, false, false);
    iter_body(1, true, true, false, false);
    for (int i = 2; i < TT; ++i)
        iter_body(i, true, true, true, false);
    iter_body(TT,     false, true,  true, false);
    iter_body(TT + 1, false, false, true, true);

    // ================= FC head (fp32) =================
    for (int i = tid; i < 54 * 64; i += 1024) fcW[(i >> 6) * 65 + (i & 63)] = w0[i];
    for (int i = tid; i < 54; i += 1024) {
        fcP[i] = b0[i]; fcP[64 + i] = g0[i]; fcP[128 + i] = be0[i];
        fcP[192 + i] = m0[i]; fcP[256 + i] = v0[i];
    }
    __syncthreads();
    for (int idx = tid; idx < BB * 54; idx += 1024) {
        const int bb = idx / 54, j = idx - bb * 54;
        float s = fcP[j];
        for (int k = 0; k < 64; ++k) s += fcW[j * 65 + k] * fcA[bb * 64 + k];
        s = (s - fcP[192 + j]) * rsqrtf(fcP[256 + j] + 1e-5f) * fcP[64 + j] + fcP[128 + j];
        fcB[bb * 64 + j] = fmaxf(s, 0.0f);
    }
    __syncthreads();

    for (int i = tid; i < 44 * 54; i += 1024) fcW[(i / 54) * 55 + (i % 54)] = w1[i];
    for (int i = tid; i < 44; i += 1024) {
        fcP[i] = b1[i]; fcP[64 + i] = g1[i]; fcP[128 + i] = be1[i];
        fcP[192 + i] = m1[i]; fcP[256 + i] = v1[i];
    }
    __syncthreads();
    for (int idx = tid; idx < BB * 44; idx += 1024) {
        const int bb = idx / 44, j = idx - bb * 44;
        float s = fcP[j];
        for (int k = 0; k < 54; ++k) s += fcW[j * 55 + k] * fcB[bb * 64 + k];
        s = (s - fcP[192 + j]) * rsqrtf(fcP[256 + j] + 1e-5f) * fcP[64 + j] + fcP[128 + j];
        fcA[bb * 64 + j] = fmaxf(s, 0.0f);
    }
    __syncthreads();

    for (int i = tid; i < 24 * 44; i += 1024) fcW[(i / 44) * 45 + (i % 44)] = w2[i];
    for (int i = tid; i < 24; i += 1024) {
        fcP[i] = b2[i]; fcP[64 + i] = g2[i]; fcP[128 + i] = be2[i];
        fcP[192 + i] = m2[i]; fcP[256 + i] = v2[i];
    }
    __syncthreads();
    for (int idx = tid; idx < BB * 24; idx += 1024) {
        const int bb = idx / 24, j = idx - bb * 24;
        float s = fcP[j];
        for (int k = 0; k < 44; ++k) s += fcW[j * 45 + k] * fcA[bb * 64 + k];
        s = (s - fcP[192 + j]) * rsqrtf(fcP[256 + j] + 1e-5f) * fcP[64 + j] + fcP[128 + j];
        fcB[bb * 64 + j] = fmaxf(s, 0.0f);
    }
    __syncthreads();

    for (int i = tid; i < 4 * 24; i += 1024) fcW[(i / 24) * 25 + (i % 24)] = w3[i];
    for (int i = tid; i < 4; i += 1024) fcP[i] = b3[i];
    __syncthreads();
    for (int idx = tid; idx < BB * 4; idx += 1024) {
        const int bb = idx / 4, j = idx - bb * 4;
        float s = fcP[j];
        for (int k = 0; k < 24; ++k) s += fcW[j * 25 + k] * fcB[bb * 64 + k];
        out[(size_t)(n0 + bb) * 4 + j] = s;
    }
}

extern "C" void kernel_launch(void* const* d_in, const int* in_sizes, int n_in,
                              void* d_out, int out_size, void* d_ws, size_t ws_size,
                              hipStream_t stream) {
    const float* p[33];
    for (int i = 0; i < 33; ++i) p[i] = (const float*)d_in[i];
    lstm_fused<<<NBLK, 1024, 0, stream>>>(
        p[0],
        p[1], p[2], p[3], p[4],
        p[5], p[6], p[7], p[8],
        p[9], p[10], p[11], p[12],
        p[13], p[14], p[15], p[16], p[17], p[18], p[19], p[20],
        p[21], p[22], p[23], p[24],
        p[25], p[26], p[27], p[28],
        p[29], p[30], p[31], p[32],
        (float*)d_out);
}